// Round 1
// baseline (499.272 us; speedup 1.0000x reference)
//
#include <hip/hip_runtime.h>

// Problem constants
#define BATCH 8
#define HDIM 64
#define WDIM 64
#define HW 4096           // 64*64
#define CCH 256           // C1 = C = C2 = 256
#define GRP 16
#define CG 16
#define KTAP 9
#define MOFF 432          // G*3*K
#define PTOT 32768        // B*H*W

typedef unsigned short u16;

// bf16 <-> f32 (RNE), header-independent
__device__ __forceinline__ u16 f2b(float f){
  unsigned int u = __float_as_uint(f);
  unsigned int rounding = 0x7FFFu + ((u >> 16) & 1u);
  return (u16)((u + rounding) >> 16);
}
__device__ __forceinline__ float b2f(u16 s){
  return __uint_as_float(((unsigned int)s) << 16);
}

// ---------------------------------------------------------------------------
// K1: conv1 1x1  h1n[p][o] = sum_c x[b,c,p'] * w1[o,c] + b1[o]   (bf16 out, NHWC)
// grid (512, 4), block 256. Tile 64p x 64o, K-chunk 16, 4x4 microtile.
// ---------------------------------------------------------------------------
__global__ __launch_bounds__(256) void k_conv1(const float* __restrict__ x,
    const float* __restrict__ w1, const float* __restrict__ b1,
    u16* __restrict__ h1n){
  __shared__ float As[16][65];  // [c][p]
  __shared__ float Bs[16][65];  // [c][o]
  const int t = threadIdx.x;
  const int tp = blockIdx.x * 64;
  const int to = blockIdx.y * 64;
  const int bimg = tp >> 12;
  const int ploc = tp & 4095;
  const int ty = t >> 4, tx = t & 15;
  float acc[4][4] = {};
  for (int kc = 0; kc < CCH; kc += 16){
    #pragma unroll
    for (int r = 0; r < 4; ++r){
      int idx = t + r * 256;
      int c_l = idx >> 6, p_l = idx & 63;
      As[c_l][p_l] = x[(size_t)(bimg * CCH + kc + c_l) * HW + ploc + p_l];
    }
    #pragma unroll
    for (int r = 0; r < 4; ++r){
      int idx = t + r * 256;
      int o_l = idx >> 4, c_l = idx & 15;
      Bs[c_l][o_l] = w1[(to + o_l) * CCH + kc + c_l];
    }
    __syncthreads();
    #pragma unroll
    for (int kk = 0; kk < 16; ++kk){
      float a[4], bv[4];
      #pragma unroll
      for (int i = 0; i < 4; ++i) a[i] = As[kk][ty * 4 + i];
      #pragma unroll
      for (int j = 0; j < 4; ++j) bv[j] = Bs[kk][tx * 4 + j];
      #pragma unroll
      for (int i = 0; i < 4; ++i)
        #pragma unroll
        for (int j = 0; j < 4; ++j) acc[i][j] += a[i] * bv[j];
    }
    __syncthreads();
  }
  float bias[4];
  #pragma unroll
  for (int j = 0; j < 4; ++j) bias[j] = b1[to + tx * 4 + j];
  #pragma unroll
  for (int i = 0; i < 4; ++i){
    ushort4 v;
    v.x = f2b(acc[i][0] + bias[0]);
    v.y = f2b(acc[i][1] + bias[1]);
    v.z = f2b(acc[i][2] + bias[2]);
    v.w = f2b(acc[i][3] + bias[3]);
    *reinterpret_cast<ushort4*>(&h1n[(size_t)(tp + ty * 4 + i) * CCH + to + tx * 4]) = v;
  }
}

// ---------------------------------------------------------------------------
// K2: offset conv  om[p][o] = sum_c h1n[p][c] * woff[o,c] + boff[o]  (bf16)
// grid (512, 7), block 256. M=432 guarded.
// ---------------------------------------------------------------------------
__global__ __launch_bounds__(256) void k_off(const u16* __restrict__ h1n,
    const float* __restrict__ woff, const float* __restrict__ boff,
    u16* __restrict__ om){
  __shared__ float As[16][65];  // [c][p]
  __shared__ float Bs[16][65];  // [c][o]
  const int t = threadIdx.x;
  const int tp = blockIdx.x * 64;
  const int to = blockIdx.y * 64;
  const int ty = t >> 4, tx = t & 15;
  float acc[4][4] = {};
  for (int kc = 0; kc < CCH; kc += 16){
    #pragma unroll
    for (int r = 0; r < 4; ++r){
      int idx = t + r * 256;
      int p_l = idx >> 4, c_l = idx & 15;
      As[c_l][p_l] = b2f(h1n[(size_t)(tp + p_l) * CCH + kc + c_l]);
    }
    #pragma unroll
    for (int r = 0; r < 4; ++r){
      int idx = t + r * 256;
      int o_l = idx >> 4, c_l = idx & 15;
      int o = to + o_l;
      Bs[c_l][o_l] = (o < MOFF) ? woff[o * CCH + kc + c_l] : 0.f;
    }
    __syncthreads();
    #pragma unroll
    for (int kk = 0; kk < 16; ++kk){
      float a[4], bv[4];
      #pragma unroll
      for (int i = 0; i < 4; ++i) a[i] = As[kk][ty * 4 + i];
      #pragma unroll
      for (int j = 0; j < 4; ++j) bv[j] = Bs[kk][tx * 4 + j];
      #pragma unroll
      for (int i = 0; i < 4; ++i)
        #pragma unroll
        for (int j = 0; j < 4; ++j) acc[i][j] += a[i] * bv[j];
    }
    __syncthreads();
  }
  const int o0 = to + tx * 4;
  if (o0 < MOFF){
    float b0 = boff[o0], b1v = boff[o0 + 1], b2v = boff[o0 + 2], b3v = boff[o0 + 3];
    #pragma unroll
    for (int i = 0; i < 4; ++i){
      int p = tp + ty * 4 + i;
      ushort4 v;
      v.x = f2b(acc[i][0] + b0);
      v.y = f2b(acc[i][1] + b1v);
      v.z = f2b(acc[i][2] + b2v);
      v.w = f2b(acc[i][3] + b3v);
      *reinterpret_cast<ushort4*>(&om[(size_t)p * MOFF + o0]) = v;
    }
  }
}

// ---------------------------------------------------------------------------
// K3: deformable sampling. One block per pixel; thread = (g, cg).
// ydcn[p][g*16+cg] = sum_k mask[g,k] * bilinear(v, p_h + off, p_w + off)
// ---------------------------------------------------------------------------
__global__ __launch_bounds__(256) void k_sample(const u16* __restrict__ h1n,
    const u16* __restrict__ om, u16* __restrict__ ydcn){
  __shared__ float oms[MOFF];
  const int p = blockIdx.x;
  const int t = threadIdx.x;
  const int b = p >> 12, hw = p & 4095;
  const int ic = hw >> 6, jc = hw & 63;

  oms[t] = b2f(om[(size_t)p * MOFF + t]);
  if (t < MOFF - 256) oms[256 + t] = b2f(om[(size_t)p * MOFF + 256 + t]);
  __syncthreads();

  const int g = t >> 4, cg = t & 15;
  const int ch = g * CG + cg;
  const u16* vbase = h1n + (size_t)b * HW * CCH;
  const int obase = g * 27;
  float acc = 0.f;
  #pragma unroll
  for (int k = 0; k < KTAP; ++k){
    const float kh = (float)(k / 3 - 1);
    const float kw = (float)(k % 3 - 1);
    float oh = oms[obase + 2 * k];
    float ow = oms[obase + 2 * k + 1];
    float m  = oms[obase + 18 + k];
    float ph = (float)ic + kh + oh;
    float pw = (float)jc + kw + ow;
    float h0f = floorf(ph), w0f = floorf(pw);
    int h0 = (int)h0f, w0 = (int)w0f;
    float ah = ph - h0f, aw = pw - w0f;
    float s = 0.f;
    {
      int hi = h0, wi = w0;
      if (hi >= 0 && hi < HDIM && wi >= 0 && wi < WDIM)
        s += (1.f - ah) * (1.f - aw) * b2f(vbase[(size_t)(hi * WDIM + wi) * CCH + ch]);
    }
    {
      int hi = h0, wi = w0 + 1;
      if (hi >= 0 && hi < HDIM && wi >= 0 && wi < WDIM)
        s += (1.f - ah) * aw * b2f(vbase[(size_t)(hi * WDIM + wi) * CCH + ch]);
    }
    {
      int hi = h0 + 1, wi = w0;
      if (hi >= 0 && hi < HDIM && wi >= 0 && wi < WDIM)
        s += ah * (1.f - aw) * b2f(vbase[(size_t)(hi * WDIM + wi) * CCH + ch]);
    }
    {
      int hi = h0 + 1, wi = w0 + 1;
      if (hi >= 0 && hi < HDIM && wi >= 0 && wi < WDIM)
        s += ah * aw * b2f(vbase[(size_t)(hi * WDIM + wi) * CCH + ch]);
    }
    acc += m * s;
  }
  ydcn[(size_t)p * CCH + t] = f2b(acc);
}

// ---------------------------------------------------------------------------
// K4: conv2 1x1 + BN + SiLU.  out[b,o,p'] = silu(bn(sum_c ydcn[p][c]*w2[o,c]))
// grid (512, 4), block 256. Output NCHW fp32.
// ---------------------------------------------------------------------------
__global__ __launch_bounds__(256) void k_conv2(const u16* __restrict__ ydcn,
    const float* __restrict__ w2, const float* __restrict__ gamma,
    const float* __restrict__ beta, const float* __restrict__ mean,
    const float* __restrict__ var, float* __restrict__ out){
  __shared__ float As[16][65];  // [c][p]
  __shared__ float Bs[16][65];  // [c][o]
  const int t = threadIdx.x;
  const int tp = blockIdx.x * 64;
  const int to = blockIdx.y * 64;
  const int ty = t >> 4, tx = t & 15;
  float acc[4][4] = {};
  for (int kc = 0; kc < CCH; kc += 16){
    #pragma unroll
    for (int r = 0; r < 4; ++r){
      int idx = t + r * 256;
      int p_l = idx >> 4, c_l = idx & 15;
      As[c_l][p_l] = b2f(ydcn[(size_t)(tp + p_l) * CCH + kc + c_l]);
    }
    #pragma unroll
    for (int r = 0; r < 4; ++r){
      int idx = t + r * 256;
      int o_l = idx >> 4, c_l = idx & 15;
      Bs[c_l][o_l] = w2[(to + o_l) * CCH + kc + c_l];
    }
    __syncthreads();
    #pragma unroll
    for (int kk = 0; kk < 16; ++kk){
      float a[4], bv[4];
      #pragma unroll
      for (int i = 0; i < 4; ++i) a[i] = As[kk][ty * 4 + i];
      #pragma unroll
      for (int j = 0; j < 4; ++j) bv[j] = Bs[kk][tx * 4 + j];
      #pragma unroll
      for (int i = 0; i < 4; ++i)
        #pragma unroll
        for (int j = 0; j < 4; ++j) acc[i][j] += a[i] * bv[j];
    }
    __syncthreads();
  }
  const int bimg = tp >> 12;
  const int ploc = tp & 4095;
  #pragma unroll
  for (int j = 0; j < 4; ++j){
    int o = to + tx * 4 + j;
    float sc = gamma[o] * rsqrtf(var[o] + 1e-5f);
    float mn = mean[o], bt = beta[o];
    float4 v;
    float vals[4];
    #pragma unroll
    for (int i = 0; i < 4; ++i){
      float y = (acc[i][j] - mn) * sc + bt;
      vals[i] = y / (1.f + expf(-y));
    }
    v.x = vals[0]; v.y = vals[1]; v.z = vals[2]; v.w = vals[3];
    *reinterpret_cast<float4*>(&out[(size_t)(bimg * CCH + o) * HW + ploc + ty * 4]) = v;
  }
}

extern "C" void kernel_launch(void* const* d_in, const int* in_sizes, int n_in,
                              void* d_out, int out_size, void* d_ws, size_t ws_size,
                              hipStream_t stream) {
  const float* x     = (const float*)d_in[0];
  const float* w1    = (const float*)d_in[1];
  const float* b1    = (const float*)d_in[2];
  const float* woff  = (const float*)d_in[3];
  const float* boff  = (const float*)d_in[4];
  const float* w2    = (const float*)d_in[5];
  const float* gamma = (const float*)d_in[6];
  const float* beta  = (const float*)d_in[7];
  const float* mean  = (const float*)d_in[8];
  const float* var   = (const float*)d_in[9];
  float* out = (float*)d_out;

  u16* h1n  = (u16*)d_ws;                           // 32768*256 bf16 = 16.78 MB
  u16* om   = h1n + (size_t)PTOT * CCH;             // 32768*432 bf16 = 28.31 MB
  u16* ydcn = om  + (size_t)PTOT * MOFF;            // 32768*256 bf16 = 16.78 MB
  (void)in_sizes; (void)n_in; (void)out_size; (void)ws_size;

  dim3 blk(256);
  k_conv1 <<<dim3(PTOT / 64, CCH / 64),  blk, 0, stream>>>(x, w1, b1, h1n);
  k_off   <<<dim3(PTOT / 64, (MOFF + 63) / 64), blk, 0, stream>>>(h1n, woff, boff, om);
  k_sample<<<dim3(PTOT),                 blk, 0, stream>>>(h1n, om, ydcn);
  k_conv2 <<<dim3(PTOT / 64, CCH / 64),  blk, 0, stream>>>(ydcn, w2, gamma, beta, mean, var, out);
}

// Round 2
// 112.876 us; speedup vs baseline: 4.4232x; 4.4232x over previous
//
#include <hip/hip_runtime.h>

#define HW 4096
#define CCH 256
#define MOFF 432
#define PTOT 32768

typedef unsigned short u16;
typedef __attribute__((ext_vector_type(8))) short short8;
typedef __attribute__((ext_vector_type(8))) unsigned short u16x8;
typedef __attribute__((ext_vector_type(4))) unsigned short u16x4;
typedef __attribute__((ext_vector_type(4))) float f32x4;

__device__ __forceinline__ u16 f2b(float f){
  unsigned int u = __float_as_uint(f);
  unsigned int rounding = 0x7FFFu + ((u >> 16) & 1u);
  return (u16)((u + rounding) >> 16);
}
__device__ __forceinline__ float b2f(u16 s){
  return __uint_as_float(((unsigned int)s) << 16);
}

// ---------------------------------------------------------------------------
// k_cvtw: weights fp32 -> bf16 (woff zero-padded to 448 rows), BN fold.
// grid 961 x 256
// ---------------------------------------------------------------------------
__global__ __launch_bounds__(256) void k_cvtw(const float* __restrict__ w1,
    const float* __restrict__ woff, const float* __restrict__ w2,
    const float* __restrict__ gamma, const float* __restrict__ beta,
    const float* __restrict__ mean, const float* __restrict__ var,
    u16* __restrict__ wb1, u16* __restrict__ wboff, u16* __restrict__ wb2,
    float* __restrict__ bnA, float* __restrict__ bnB){
  int r = blockIdx.x, t = threadIdx.x;
  if (r < 256) wb1[r*256 + t] = f2b(w1[r*256 + t]);
  else if (r < 704){ int o = r - 256; wboff[o*256 + t] = (o < MOFF) ? f2b(woff[o*256 + t]) : (u16)0; }
  else if (r < 960){ int o = r - 704; wb2[o*256 + t] = f2b(w2[o*256 + t]); }
  else if (t < 256){
    float sc = gamma[t] * rsqrtf(var[t] + 1e-5f);
    bnA[t] = sc;
    bnB[t] = beta[t] - mean[t] * sc;
  }
}

// ---------------------------------------------------------------------------
// k_xt: x fp32 NCHW -> xT bf16 [p][c]. grid (64, 4, 8) x 256. 64x64 LDS tile.
// ---------------------------------------------------------------------------
__global__ __launch_bounds__(256) void k_xt(const float* __restrict__ x,
    u16* __restrict__ xT){
  __shared__ float tile[64][65];
  const int pb = blockIdx.x * 64, cb = blockIdx.y * 64, b = blockIdx.z;
  const int t = threadIdx.x;
  const float* src = x + ((size_t)(b * CCH + cb)) * HW + pb;
  #pragma unroll
  for (int pass = 0; pass < 4; ++pass){
    int c_l = pass * 16 + (t >> 4);
    int pq = (t & 15) * 4;
    float4 v = *reinterpret_cast<const float4*>(&src[(size_t)c_l * HW + pq]);
    tile[pq + 0][c_l] = v.x; tile[pq + 1][c_l] = v.y;
    tile[pq + 2][c_l] = v.z; tile[pq + 3][c_l] = v.w;
  }
  __syncthreads();
  #pragma unroll
  for (int pass = 0; pass < 4; ++pass){
    int p_l = pass * 16 + (t >> 4);
    int cq = (t & 15) * 4;
    u16x4 o4;
    #pragma unroll
    for (int j = 0; j < 4; ++j) o4[j] = f2b(tile[p_l][cq + j]);
    *reinterpret_cast<u16x4*>(&xT[((size_t)b * HW + pb + p_l) * CCH + cb + cq]) = o4;
  }
}

// ---------------------------------------------------------------------------
// k_gemm: C[M=32768][N] = A[p][k] * B[n][k]^T, bf16 MFMA 16x16x32.
// Block: 256 thr (4 waves 2x2), tile 128 x BN, BK=32, K=256.
// SILU=false: C = acc + bias[o], bf16 out via LDS-transpose (ldc runtime, GUARD cols < NL).
// SILU=true : y = acc*bias[o] + bnB[o]; out = y*sigmoid(y), fp32 NCHW direct stores.
// ---------------------------------------------------------------------------
template<int BN, bool GUARD, bool SILU>
__global__ __launch_bounds__(256) void k_gemm(const u16* __restrict__ A,
    const u16* __restrict__ Bw, const float* __restrict__ bias,
    const float* __restrict__ bnB, void* __restrict__ Cout, int ldc, int NL){
  constexpr int WN = BN / 2;
  constexpr int MF = 4;
  constexpr int NF = WN / 16;
  constexpr int BOFF = 128 * 40;
  constexpr int STG = (128 + BN) * 40;
  constexpr int CMAT = 128 * (BN + 8);
  constexpr int SM = SILU ? STG : (STG > CMAT ? STG : CMAT);
  __shared__ __align__(16) u16 smem[SM];

  const int t = threadIdx.x;
  const int tm = blockIdx.x * 128;
  const int tn = blockIdx.y * BN;
  const int lane = t & 63;
  const int wid = t >> 6;
  const int wr = wid >> 1, wc = wid & 1;

  f32x4 acc[MF][NF] = {};

  for (int kc = 0; kc < 256; kc += 32){
    #pragma unroll
    for (int i = 0; i < 2; ++i){
      int v = t + i * 256;
      int row = v >> 2, cq = v & 3;
      *reinterpret_cast<u16x8*>(&smem[row * 40 + cq * 8]) =
        *reinterpret_cast<const u16x8*>(&A[(size_t)(tm + row) * 256 + kc + cq * 8]);
    }
    constexpr int BV = BN * 4 / 256;
    #pragma unroll
    for (int i = 0; i < BV; ++i){
      int v = t + i * 256;
      int row = v >> 2, cq = v & 3;
      *reinterpret_cast<u16x8*>(&smem[BOFF + row * 40 + cq * 8]) =
        *reinterpret_cast<const u16x8*>(&Bw[(size_t)(tn + row) * 256 + kc + cq * 8]);
    }
    __syncthreads();
    short8 af[MF], bf[NF];
    #pragma unroll
    for (int m = 0; m < MF; ++m)
      af[m] = *reinterpret_cast<const short8*>(
        &smem[(wr * 64 + m * 16 + (lane & 15)) * 40 + (lane >> 4) * 8]);
    #pragma unroll
    for (int n = 0; n < NF; ++n)
      bf[n] = *reinterpret_cast<const short8*>(
        &smem[BOFF + (wc * WN + n * 16 + (lane & 15)) * 40 + (lane >> 4) * 8]);
    #pragma unroll
    for (int m = 0; m < MF; ++m)
      #pragma unroll
      for (int n = 0; n < NF; ++n)
        acc[m][n] = __builtin_amdgcn_mfma_f32_16x16x32_bf16(af[m], bf[n], acc[m][n], 0, 0, 0);
    __syncthreads();
  }

  if constexpr (SILU){
    const int bimg = tm >> 12;
    const int ploc = tm & 4095;
    float* outp = (float*)Cout;
    #pragma unroll
    for (int n = 0; n < NF; ++n){
      int o = tn + wc * WN + n * 16 + (lane & 15);
      float sA = bias[o], sB = bnB[o];
      #pragma unroll
      for (int m = 0; m < MF; ++m){
        int prow = wr * 64 + m * 16 + ((lane >> 4) << 2);
        f32x4 st;
        #pragma unroll
        for (int j = 0; j < 4; ++j){
          float y = acc[m][n][j] * sA + sB;
          st[j] = y / (1.f + expf(-y));
        }
        *reinterpret_cast<f32x4*>(&outp[((size_t)(bimg * 256 + o)) * HW + ploc + prow]) = st;
      }
    }
  } else {
    constexpr int CP = BN + 8;
    u16* C_l = smem;
    #pragma unroll
    for (int n = 0; n < NF; ++n){
      int col = wc * WN + n * 16 + (lane & 15);
      int o = tn + col;
      float bi = (!GUARD || o < NL) ? bias[o] : 0.f;
      #pragma unroll
      for (int m = 0; m < MF; ++m){
        int r0 = wr * 64 + m * 16 + ((lane >> 4) << 2);
        #pragma unroll
        for (int j = 0; j < 4; ++j)
          C_l[(r0 + j) * CP + col] = f2b(acc[m][n][j] + bi);
      }
    }
    __syncthreads();
    constexpr int SEG = BN / 8;       // vec8 segments per row
    constexpr int RPP = 256 / SEG;    // rows per pass
    u16* Co = (u16*)Cout;
    #pragma unroll
    for (int pass = 0; pass < 128 / RPP; ++pass){
      int row = pass * RPP + t / SEG;
      int sg = t % SEG;
      int oc = tn + sg * 8;
      if (!GUARD || oc + 8 <= NL)
        *reinterpret_cast<u16x8*>(&Co[(size_t)(tm + row) * ldc + oc]) =
          *reinterpret_cast<const u16x8*>(&C_l[row * CP + sg * 8]);
    }
  }
}

// ---------------------------------------------------------------------------
// k_sample: 8 pixels/block, 32 lanes/pixel (16 groups x 2 halves),
// each lane = 8 contiguous channels, all gathers 16B ushort8.
// ---------------------------------------------------------------------------
__global__ __launch_bounds__(256) void k_sample(const u16* __restrict__ h1n,
    const u16* __restrict__ om, u16* __restrict__ ydcn){
  __shared__ __align__(16) u16 oms[8 * MOFF];
  const int t = threadIdx.x;
  const int pblk = blockIdx.x * 8;
  {
    const u16* src = om + (size_t)pblk * MOFF;
    *reinterpret_cast<u16x8*>(&oms[t * 8]) =
      *reinterpret_cast<const u16x8*>(&src[t * 8]);
    if (t < 176)
      *reinterpret_cast<u16x8*>(&oms[(256 + t) * 8]) =
        *reinterpret_cast<const u16x8*>(&src[(256 + t) * 8]);
  }
  __syncthreads();

  const int pix = t >> 5, s = t & 31;
  const int g = s >> 1, c0 = g * 16 + (s & 1) * 8;
  const int p = pblk + pix;
  const int b = p >> 12, hw = p & 4095;
  const int ic = hw >> 6, jc = hw & 63;
  const u16* ob = &oms[pix * MOFF + g * 27];
  const u16* vb = h1n + (size_t)b * HW * CCH + c0;

  float acc[8] = {};
  #pragma unroll
  for (int k = 0; k < 9; ++k){
    float oh = b2f(ob[2 * k]);
    float ow = b2f(ob[2 * k + 1]);
    float m  = b2f(ob[18 + k]);
    float ph = (float)(ic + (k / 3) - 1) + oh;
    float pw = (float)(jc + (k % 3) - 1) + ow;
    float h0f = floorf(ph), w0f = floorf(pw);
    int h0 = (int)h0f, w0 = (int)w0f;
    float ah = ph - h0f, aw = pw - w0f;
    float cw[4];
    cw[0] = m * (1.f - ah) * (1.f - aw);
    cw[1] = m * (1.f - ah) * aw;
    cw[2] = m * ah * (1.f - aw);
    cw[3] = m * ah * aw;
    #pragma unroll
    for (int c = 0; c < 4; ++c){
      int hi = h0 + (c >> 1);
      int wi = w0 + (c & 1);
      if (hi >= 0 && hi < 64 && wi >= 0 && wi < 64){
        u16x8 val = *reinterpret_cast<const u16x8*>(&vb[(size_t)(hi * 64 + wi) * CCH]);
        float coef = cw[c];
        #pragma unroll
        for (int j = 0; j < 8; ++j) acc[j] += coef * b2f(val[j]);
      }
    }
  }
  u16x8 o8;
  #pragma unroll
  for (int j = 0; j < 8; ++j) o8[j] = f2b(acc[j]);
  *reinterpret_cast<u16x8*>(&ydcn[(size_t)p * CCH + c0]) = o8;
}

extern "C" void kernel_launch(void* const* d_in, const int* in_sizes, int n_in,
                              void* d_out, int out_size, void* d_ws, size_t ws_size,
                              hipStream_t stream) {
  const float* x     = (const float*)d_in[0];
  const float* w1    = (const float*)d_in[1];
  const float* b1    = (const float*)d_in[2];
  const float* woff  = (const float*)d_in[3];
  const float* boff  = (const float*)d_in[4];
  const float* w2    = (const float*)d_in[5];
  const float* gamma = (const float*)d_in[6];
  const float* beta  = (const float*)d_in[7];
  const float* mean  = (const float*)d_in[8];
  const float* var   = (const float*)d_in[9];
  float* out = (float*)d_out;
  (void)in_sizes; (void)n_in; (void)out_size; (void)ws_size;

  u16* h1n   = (u16*)d_ws;                                  // 32768*256
  u16* om    = h1n + (size_t)PTOT * CCH;                    // 32768*432
  u16* xT    = om + (size_t)PTOT * MOFF;                    // 32768*256 (aliased with ydcn)
  u16* ydcn  = xT;
  u16* wb1   = xT + (size_t)PTOT * CCH;                     // 256*256
  u16* wboff = wb1 + 256 * 256;                             // 448*256 (zero-padded)
  u16* wb2   = wboff + 448 * 256;                           // 256*256
  float* bnA = (float*)(wb2 + 256 * 256);                   // 256 f32
  float* bnB = bnA + 256;                                   // 256 f32

  dim3 blk(256);
  k_cvtw<<<dim3(961), blk, 0, stream>>>(w1, woff, w2, gamma, beta, mean, var,
                                        wb1, wboff, wb2, bnA, bnB);
  k_xt<<<dim3(64, 4, 8), blk, 0, stream>>>(x, xT);
  k_gemm<128, false, false><<<dim3(PTOT / 128, 2), blk, 0, stream>>>(
      xT, wb1, b1, nullptr, (void*)h1n, 256, 256);
  k_gemm<64, true, false><<<dim3(PTOT / 128, 7), blk, 0, stream>>>(
      h1n, wboff, boff, nullptr, (void*)om, MOFF, MOFF);
  k_sample<<<dim3(PTOT / 8), blk, 0, stream>>>(h1n, om, ydcn);
  k_gemm<128, false, true><<<dim3(PTOT / 128, 2), blk, 0, stream>>>(
      ydcn, wb2, bnA, bnB, (void*)out, 0, 256);
}